// Round 6
// baseline (62.605 us; speedup 1.0000x reference)
//
#include <hip/hip_runtime.h>
#include <hip/hip_bf16.h>
#include <math.h>

#define DDIM 32
#define KMIX 8
#define TPW 5  // 16-row tiles per wave

typedef short bf16x8 __attribute__((ext_vector_type(8)));
typedef float f32x4 __attribute__((ext_vector_type(4)));

__device__ __forceinline__ ushort to_bf16_rne(float f) {
    unsigned u = __builtin_bit_cast(unsigned, f);
    u = (u + 0x7FFFu + ((u >> 16) & 1u)) >> 16;
    return (ushort)u;
}

// ---------- prep: GJ inverse (SPD, no pivoting) -> Cholesky(Sigma^-1) -> panels.
__global__ __launch_bounds__(1024) void gmm_prep(
    const float* __restrict__ S, const float* __restrict__ mus,
    const float* __restrict__ phis, ushort* __restrict__ Wtg,
    ushort* __restrict__ Upan, float* __restrict__ pa2, float* __restrict__ pc)
{
    __shared__ float aug[DDIM][2 * DDIM + 2];  // stride 66
    __shared__ float ch[DDIM][DDIM + 1];       // stride 33
    __shared__ float pivsave[DDIM];
    __shared__ float amuL[DDIM];
    __shared__ float logL[DDIM];
    const int k = blockIdx.x;
    const int t = threadIdx.x;
    const int r = t >> 5, c = t & 31;

    aug[r][c]      = S[k * 1024 + r * 32 + c];
    aug[r][c + 32] = (c == r) ? 1.f : 0.f;
    __syncthreads();

    for (int p = 0; p < DDIM; ++p) {
        const float piv   = aug[p][p];
        const float f     = aug[r][p];
        const float prow  = aug[p][c];
        const float prow2 = aug[p][c + 32];
        __syncthreads();
        const float ip = 1.f / piv;
        if (r == p) {
            aug[r][c]      = prow * ip;
            aug[r][c + 32] = prow2 * ip;
            if (c == 0) pivsave[p] = piv;
        } else {
            const float fi = f * ip;
            aug[r][c]      = fmaf(-fi, prow,  aug[r][c]);
            aug[r][c + 32] = fmaf(-fi, prow2, aug[r][c + 32]);
        }
        __syncthreads();
    }

    if (t < DDIM) {
        float acc = 0.f;
        for (int d = 0; d < DDIM; ++d)
            acc = fmaf(aug[t][32 + d], mus[k * 32 + d], acc);
        amuL[t] = acc;
        logL[t] = logf(fabsf(pivsave[t]));
    }
    ch[r][c] = aug[r][32 + c];
    __syncthreads();

    // Cholesky (lower) of Ainv: 2-barrier pre-read pattern.
    for (int j = 0; j < DDIM; ++j) {
        const float djj = ch[j][j];
        const float cr  = ch[r][j];
        const float cc  = ch[c][j];
        __syncthreads();
        if (c == j) {
            ch[r][j] = (r >= j) ? cr * rsqrtf(djj) : 0.f;
        } else if (r > j && c > j) {
            ch[r][c] = fmaf(-cr * __builtin_amdgcn_rcpf(djj), cc, ch[r][c]);
        }
        __syncthreads();
    }

    {
        const int e = t >> 5, d = t & 31;
        const float fv = (d >= e) ? ch[d][e] : 0.f;
        Wtg[k * 1024 + e * 32 + d] = to_bf16_rne(fv);
    }
    if (t < DDIM)
        Upan[k * 32 + t] = to_bf16_rne(phis[k] * 1.4426950408889634f * amuL[t]);
    if (k == 0 && t >= 256 && t < 512) Upan[t] = 0;  // U rows 8..15 = 0
    if (t == 0) {
        float ldet = 0.f, muAmu = 0.f;
        for (int i = 0; i < DDIM; ++i) {
            ldet += logL[i];
            muAmu = fmaf(amuL[i], mus[k * 32 + i], muAmu);
        }
        const float eld = expf(0.5f * (DDIM * 1.8378770664093453f + ldet));
        const float LOG2E = 1.4426950408889634f;
        pa2[k] = -0.5f * phis[k] * LOG2E;
        pc[k]  = (-0.5f * phis[k] * muAmu - phis[k] * eld) * LOG2E;
    }
}

// ---------- DPP helpers -----------------------------------------------------
template <int CTRL>
__device__ __forceinline__ float dpp_add(float v) {
    int t = __builtin_amdgcn_update_dpp(0, __builtin_bit_cast(int, v), CTRL, 0xF, 0xF, true);
    return v + __builtin_bit_cast(float, t);
}
template <int CTRL>
__device__ __forceinline__ float dpp_max(float v) {
    int t = __builtin_amdgcn_update_dpp(0, __builtin_bit_cast(int, v), CTRL, 0xF, 0xF, true);
    return fmaxf(v, __builtin_bit_cast(float, t));
}
__device__ __forceinline__ float sel4(float a0, float a1, float a2, float a3, int r) {
    float b0 = (r & 1) ? a1 : a0;
    float b1 = (r & 1) ? a3 : a2;
    return (r & 2) ? b1 : b0;
}
__device__ __forceinline__ float bperm_f(int addr, float v) {
    return __builtin_bit_cast(float, __builtin_amdgcn_ds_bpermute(addr, __builtin_bit_cast(int, v)));
}

// ---------- main: q = ||X*L||^2 via MFMA self-dot; linear term via 1 MFMA ---
// Lane (g = lane>>4, c = lane&15) finalizes row r1 = g*4+(c&3), k-pair p = c>>2.
// launch_bounds(256,4): cap VGPR at 128 -> 4 waves/SIMD (16/CU) for latency hiding.
__global__ __launch_bounds__(256, 4) void gmm_main(
    const float* __restrict__ X, const ushort* __restrict__ Wtg,
    const ushort* __restrict__ Upan, const float* __restrict__ pa2g,
    const float* __restrict__ pcg, float* __restrict__ out, int N)
{
    const int tid = threadIdx.x;
    const int lane = tid & 63;
    const int wid = tid >> 6;
    const int g = lane >> 4;
    const int c = lane & 15;
    const int rsel = c & 3;
    const int r1 = g * 4 + rsel;       // output row within tile
    const int p = c >> 2;              // output k-pair (k = 2p, 2p+1)

    bf16x8 wf0[KMIX], wf1[KMIX];
#pragma unroll
    for (int k = 0; k < KMIX; ++k) {
        wf0[k] = *(const bf16x8*)(Wtg + (size_t)((k * 32 + c) * 32) + g * 8);
        wf1[k] = *(const bf16x8*)(Wtg + (size_t)((k * 32 + 16 + c) * 32) + g * 8);
    }
    const bf16x8 uf = *(const bf16x8*)(Upan + c * 32 + g * 8);  // A-frag of U
    const float paA = pa2g[2 * p], paB = pa2g[2 * p + 1];
    const float pcA = pcg[2 * p],  pcB = pcg[2 * p + 1];
    const int src_byte = (((p >> 1) * 16 + r1) << 2);

    const int ntiles = N >> 4;
    const int tile0 = (blockIdx.x * 4 + wid) * TPW;
    const float* lp = X + (size_t)tile0 * 512 + c * 32 + g * 8;
    float* op = out + (size_t)(tile0 * 16 + r1) * 8 + p * 2;

    const f32x4 zro = {0.f, 0.f, 0.f, 0.f};
    float4 a0 = {0,0,0,0}, a1 = {0,0,0,0};
    if (tile0 < ntiles) { a0 = *(const float4*)lp; a1 = *(const float4*)(lp + 4); }

#pragma unroll
    for (int it = 0; it < TPW; ++it) {
        const int tile = tile0 + it;
        float4 b0 = a0, b1 = a1;
        if (it + 1 < TPW && tile + 1 < ntiles) {
            b0 = *(const float4*)(lp + 512);
            b1 = *(const float4*)(lp + 516);
        }
        if (tile < ntiles) {
            int4 xi;
            xi.x = __builtin_amdgcn_perm(__builtin_bit_cast(unsigned, a0.y), __builtin_bit_cast(unsigned, a0.x), 0x07060302u);
            xi.y = __builtin_amdgcn_perm(__builtin_bit_cast(unsigned, a0.w), __builtin_bit_cast(unsigned, a0.z), 0x07060302u);
            xi.z = __builtin_amdgcn_perm(__builtin_bit_cast(unsigned, a1.y), __builtin_bit_cast(unsigned, a1.x), 0x07060302u);
            xi.w = __builtin_amdgcn_perm(__builtin_bit_cast(unsigned, a1.w), __builtin_bit_cast(unsigned, a1.z), 0x07060302u);
            const bf16x8 xf = __builtin_bit_cast(bf16x8, xi);

            const f32x4 lin = __builtin_amdgcn_mfma_f32_16x16x32_bf16(uf, xf, zro, 0, 0, 0);

            float qa = 0.f, qb = 0.f;
#pragma unroll
            for (int k = 0; k < KMIX; ++k) {
                f32x4 acc0 = __builtin_amdgcn_mfma_f32_16x16x32_bf16(xf, wf0[k], zro, 0, 0, 0);
                f32x4 acc1 = __builtin_amdgcn_mfma_f32_16x16x32_bf16(xf, wf1[k], zro, 0, 0, 0);
                float p0 = fmaf(acc1[0], acc1[0], acc0[0] * acc0[0]);
                float p1 = fmaf(acc1[1], acc1[1], acc0[1] * acc0[1]);
                float p2 = fmaf(acc1[2], acc1[2], acc0[2] * acc0[2]);
                float p3 = fmaf(acc1[3], acc1[3], acc0[3] * acc0[3]);
                p0 = dpp_add<0xB1>(p0); p0 = dpp_add<0x4E>(p0);
                p1 = dpp_add<0xB1>(p1); p1 = dpp_add<0x4E>(p1);
                p2 = dpp_add<0xB1>(p2); p2 = dpp_add<0x4E>(p2);
                p3 = dpp_add<0xB1>(p3); p3 = dpp_add<0x4E>(p3);
                float v = sel4(p0, p1, p2, p3, rsel);   // keep row g*4+(c&3)
                v = dpp_add<0x124>(v);                  // row_ror:4
                v = dpp_add<0x128>(v);                  // row_ror:8
                // accumulate only this lane's k-pair (compile-time k, runtime p)
                if ((k >> 1) == 0) { if (p == 0) { if (k & 1) qb = v; else qa = v; } }
                if ((k >> 1) == 1) { if (p == 1) { if (k & 1) qb = v; else qa = v; } }
                if ((k >> 1) == 2) { if (p == 2) { if (k & 1) qb = v; else qa = v; } }
                if ((k >> 1) == 3) { if (p == 3) { if (k & 1) qb = v; else qa = v; } }
            }

            const float l0 = bperm_f(src_byte, lin[0]);
            const float l1 = bperm_f(src_byte, lin[1]);
            const float l2 = bperm_f(src_byte, lin[2]);
            const float l3 = bperm_f(src_byte, lin[3]);
            const float lina = (p & 1) ? l2 : l0;
            const float linb = (p & 1) ? l3 : l1;
            const float aka = fmaf(paA, qa, pcA) + lina;
            const float akb = fmaf(paB, qb, pcB) + linb;

            float m = fmaxf(aka, akb);
            m = dpp_max<0x124>(m); m = dpp_max<0x128>(m);
            const float ea = __builtin_amdgcn_exp2f(aka - m);
            const float eb = __builtin_amdgcn_exp2f(akb - m);
            float s = ea + eb;
            s = dpp_add<0x124>(s); s = dpp_add<0x128>(s);
            const float inv = __builtin_amdgcn_rcpf(s);
            *(float2*)op = make_float2(ea * inv, eb * inv);
        }
        a0 = b0; a1 = b1;
        lp += 512;
        op += 128;
    }
}

extern "C" void kernel_launch(void* const* d_in, const int* in_sizes, int n_in,
                              void* d_out, int out_size, void* d_ws, size_t ws_size,
                              hipStream_t stream) {
    const float* X    = (const float*)d_in[0];
    const float* mus  = (const float*)d_in[1];
    const float* sig  = (const float*)d_in[2];
    const float* phis = (const float*)d_in[3];
    float* out = (float*)d_out;

    float* ws    = (float*)d_ws;
    float* pa2   = ws;                   // 8 f32
    float* pc    = ws + 8;               // 8 f32
    ushort* Upan = (ushort*)(ws + 16);   // 512 bf16 (1 KiB)
    ushort* Wtg  = (ushort*)(ws + 272);  // 8192 bf16, byte off 1088 (16B-aligned)

    const int N = in_sizes[0] / DDIM;

    gmm_prep<<<KMIX, 1024, 0, stream>>>(sig, mus, phis, Wtg, Upan, pa2, pc);

    const int ntiles = N >> 4;
    const int grid = (ntiles + 4 * TPW - 1) / (4 * TPW);
    gmm_main<<<grid, 256, 0, stream>>>(X, Wtg, Upan, pa2, pc, out, N);
}

// Round 7
// 56.001 us; speedup vs baseline: 1.1179x; 1.1179x over previous
//
#include <hip/hip_runtime.h>
#include <hip/hip_bf16.h>
#include <math.h>

#define DDIM 32
#define KMIX 8
#define TPW 5  // 16-row tiles per wave

typedef short bf16x8 __attribute__((ext_vector_type(8)));
typedef float f32x4 __attribute__((ext_vector_type(4)));

__device__ __forceinline__ ushort to_bf16_rne(float f) {
    unsigned u = __builtin_bit_cast(unsigned, f);
    u = (u + 0x7FFFu + ((u >> 16) & 1u)) >> 16;
    return (ushort)u;
}

// ---------- prep: GJ inverse (SPD, no pivoting) -> Cholesky(Sigma^-1) -> panels.
// Wtg is written in per-lane MFMA-fragment order:
//   Wtg[k*1024 + h*512 + lane*8 + j] = L_k[d = (lane>>4)*8 + j][e = h*16 + (lane&15)]
// so main can bulk-copy it to LDS and each lane reads its 16B frag conflict-free.
__global__ __launch_bounds__(1024) void gmm_prep(
    const float* __restrict__ S, const float* __restrict__ mus,
    const float* __restrict__ phis, ushort* __restrict__ Wtg,
    ushort* __restrict__ Upan, float* __restrict__ pa2, float* __restrict__ pc)
{
    __shared__ float aug[DDIM][2 * DDIM + 2];  // stride 66
    __shared__ float ch[DDIM][DDIM + 1];       // stride 33
    __shared__ float pivsave[DDIM];
    __shared__ float amuL[DDIM];
    __shared__ float logL[DDIM];
    const int k = blockIdx.x;
    const int t = threadIdx.x;
    const int r = t >> 5, c = t & 31;

    aug[r][c]      = S[k * 1024 + r * 32 + c];
    aug[r][c + 32] = (c == r) ? 1.f : 0.f;
    __syncthreads();

    for (int p = 0; p < DDIM; ++p) {
        const float piv   = aug[p][p];
        const float f     = aug[r][p];
        const float prow  = aug[p][c];
        const float prow2 = aug[p][c + 32];
        __syncthreads();
        const float ip = 1.f / piv;
        if (r == p) {
            aug[r][c]      = prow * ip;
            aug[r][c + 32] = prow2 * ip;
            if (c == 0) pivsave[p] = piv;
        } else {
            const float fi = f * ip;
            aug[r][c]      = fmaf(-fi, prow,  aug[r][c]);
            aug[r][c + 32] = fmaf(-fi, prow2, aug[r][c + 32]);
        }
        __syncthreads();
    }

    if (t < DDIM) {
        float acc = 0.f;
        for (int d = 0; d < DDIM; ++d)
            acc = fmaf(aug[t][32 + d], mus[k * 32 + d], acc);
        amuL[t] = acc;
        logL[t] = logf(fabsf(pivsave[t]));
    }
    ch[r][c] = aug[r][32 + c];
    __syncthreads();

    // Cholesky (lower) of Ainv: 2-barrier pre-read pattern.
    for (int j = 0; j < DDIM; ++j) {
        const float djj = ch[j][j];
        const float cr  = ch[r][j];
        const float cc  = ch[c][j];
        __syncthreads();
        if (c == j) {
            ch[r][j] = (r >= j) ? cr * rsqrtf(djj) : 0.f;
        } else if (r > j && c > j) {
            ch[r][c] = fmaf(-cr * __builtin_amdgcn_rcpf(djj), cc, ch[r][c]);
        }
        __syncthreads();
    }

    // per-lane fragment order: t = h*512 + lane*8 + j
    {
        const int h    = t >> 9;
        const int lane = (t >> 3) & 63;
        const int j    = t & 7;
        const int d = (lane >> 4) * 8 + j;
        const int e = h * 16 + (lane & 15);
        const float fv = (d >= e) ? ch[d][e] : 0.f;
        Wtg[k * 1024 + t] = to_bf16_rne(fv);
    }
    if (t < DDIM)
        Upan[k * 32 + t] = to_bf16_rne(phis[k] * 1.4426950408889634f * amuL[t]);
    if (k == 0 && t >= 256 && t < 512) Upan[t] = 0;  // U rows 8..15 = 0
    if (t == 0) {
        float ldet = 0.f, muAmu = 0.f;
        for (int i = 0; i < DDIM; ++i) {
            ldet += logL[i];
            muAmu = fmaf(amuL[i], mus[k * 32 + i], muAmu);
        }
        const float eld = expf(0.5f * (DDIM * 1.8378770664093453f + ldet));
        const float LOG2E = 1.4426950408889634f;
        pa2[k] = -0.5f * phis[k] * LOG2E;
        pc[k]  = (-0.5f * phis[k] * muAmu - phis[k] * eld) * LOG2E;
    }
}

// ---------- DPP helpers -----------------------------------------------------
template <int CTRL>
__device__ __forceinline__ float dpp_add(float v) {
    int t = __builtin_amdgcn_update_dpp(0, __builtin_bit_cast(int, v), CTRL, 0xF, 0xF, true);
    return v + __builtin_bit_cast(float, t);
}
template <int CTRL>
__device__ __forceinline__ float dpp_max(float v) {
    int t = __builtin_amdgcn_update_dpp(0, __builtin_bit_cast(int, v), CTRL, 0xF, 0xF, true);
    return fmaxf(v, __builtin_bit_cast(float, t));
}
__device__ __forceinline__ float sel4(float a0, float a1, float a2, float a3, int r) {
    float b0 = (r & 1) ? a1 : a0;
    float b1 = (r & 1) ? a3 : a2;
    return (r & 2) ? b1 : b0;
}
__device__ __forceinline__ float bperm_f(int addr, float v) {
    return __builtin_bit_cast(float, __builtin_amdgcn_ds_bpermute(addr, __builtin_bit_cast(int, v)));
}

// ---------- main: q = ||X*L||^2 via MFMA self-dot; W frags from LDS table ---
// Lane (g = lane>>4, c = lane&15) finalizes row r1 = g*4+(c&3), k-pair p = c>>2.
// launch_bounds(256,6): cap VGPR at ~85 -> 6 waves/SIMD for latency hiding.
__global__ __launch_bounds__(256, 6) void gmm_main(
    const float* __restrict__ X, const ushort* __restrict__ Wtg,
    const ushort* __restrict__ Upan, const float* __restrict__ pa2g,
    const float* __restrict__ pcg, float* __restrict__ out, int N)
{
    __shared__ ushort wtab[KMIX * 1024];  // 16 KiB: [k][h][lane][8 bf16]
    const int tid = threadIdx.x;
    const int lane = tid & 63;
    const int wid = tid >> 6;
    const int g = lane >> 4;
    const int c = lane & 15;
    const int rsel = c & 3;
    const int r1 = g * 4 + rsel;       // output row within tile
    const int p = c >> 2;              // output k-pair (k = 2p, 2p+1)

    // bulk-copy fragment table to LDS (1024 float4 chunks, conflict-free)
    {
        const float4* src = (const float4*)Wtg;
        float4* dst = (float4*)wtab;
#pragma unroll
        for (int i = 0; i < 4; ++i) dst[tid + 256 * i] = src[tid + 256 * i];
    }

    const bf16x8 uf = *(const bf16x8*)(Upan + c * 32 + g * 8);  // A-frag of U
    const float paA = pa2g[2 * p], paB = pa2g[2 * p + 1];
    const float pcA = pcg[2 * p],  pcB = pcg[2 * p + 1];
    const int src_byte = (((p >> 1) * 16 + r1) << 2);

    const int ntiles = N >> 4;
    const int tile0 = (blockIdx.x * 4 + wid) * TPW;
    const float* lp = X + (size_t)tile0 * 512 + c * 32 + g * 8;
    float* op = out + (size_t)(tile0 * 16 + r1) * 8 + p * 2;

    const f32x4 zro = {0.f, 0.f, 0.f, 0.f};
    float4 a0 = {0,0,0,0}, a1 = {0,0,0,0};
    if (tile0 < ntiles) { a0 = *(const float4*)lp; a1 = *(const float4*)(lp + 4); }

    __syncthreads();  // wtab ready

#pragma unroll
    for (int it = 0; it < TPW; ++it) {
        const int tile = tile0 + it;
        float4 b0 = a0, b1 = a1;
        if (it + 1 < TPW && tile + 1 < ntiles) {
            b0 = *(const float4*)(lp + 512);
            b1 = *(const float4*)(lp + 516);
        }
        if (tile < ntiles) {
            int4 xi;
            xi.x = __builtin_amdgcn_perm(__builtin_bit_cast(unsigned, a0.y), __builtin_bit_cast(unsigned, a0.x), 0x07060302u);
            xi.y = __builtin_amdgcn_perm(__builtin_bit_cast(unsigned, a0.w), __builtin_bit_cast(unsigned, a0.z), 0x07060302u);
            xi.z = __builtin_amdgcn_perm(__builtin_bit_cast(unsigned, a1.y), __builtin_bit_cast(unsigned, a1.x), 0x07060302u);
            xi.w = __builtin_amdgcn_perm(__builtin_bit_cast(unsigned, a1.w), __builtin_bit_cast(unsigned, a1.z), 0x07060302u);
            const bf16x8 xf = __builtin_bit_cast(bf16x8, xi);

            const f32x4 lin = __builtin_amdgcn_mfma_f32_16x16x32_bf16(uf, xf, zro, 0, 0, 0);

            // launder LDS base so LICM can't hoist the (loop-invariant) frag reads
            int la = lane * 16;
            asm volatile("" : "+v"(la));
            const char* wb = (const char*)wtab + la;

            float qa = 0.f, qb = 0.f;
#pragma unroll
            for (int k = 0; k < KMIX; ++k) {
                const bf16x8 wf0k = *(const bf16x8*)(wb + (k * 2 + 0) * 1024);
                const bf16x8 wf1k = *(const bf16x8*)(wb + (k * 2 + 1) * 1024);
                f32x4 acc0 = __builtin_amdgcn_mfma_f32_16x16x32_bf16(xf, wf0k, zro, 0, 0, 0);
                f32x4 acc1 = __builtin_amdgcn_mfma_f32_16x16x32_bf16(xf, wf1k, zro, 0, 0, 0);
                float p0 = fmaf(acc1[0], acc1[0], acc0[0] * acc0[0]);
                float p1 = fmaf(acc1[1], acc1[1], acc0[1] * acc0[1]);
                float p2 = fmaf(acc1[2], acc1[2], acc0[2] * acc0[2]);
                float p3 = fmaf(acc1[3], acc1[3], acc0[3] * acc0[3]);
                p0 = dpp_add<0xB1>(p0); p0 = dpp_add<0x4E>(p0);
                p1 = dpp_add<0xB1>(p1); p1 = dpp_add<0x4E>(p1);
                p2 = dpp_add<0xB1>(p2); p2 = dpp_add<0x4E>(p2);
                p3 = dpp_add<0xB1>(p3); p3 = dpp_add<0x4E>(p3);
                float v = sel4(p0, p1, p2, p3, rsel);   // keep row g*4+(c&3)
                v = dpp_add<0x124>(v);                  // row_ror:4
                v = dpp_add<0x128>(v);                  // row_ror:8
                if ((k >> 1) == 0) { if (p == 0) { if (k & 1) qb = v; else qa = v; } }
                if ((k >> 1) == 1) { if (p == 1) { if (k & 1) qb = v; else qa = v; } }
                if ((k >> 1) == 2) { if (p == 2) { if (k & 1) qb = v; else qa = v; } }
                if ((k >> 1) == 3) { if (p == 3) { if (k & 1) qb = v; else qa = v; } }
            }

            const float l0 = bperm_f(src_byte, lin[0]);
            const float l1 = bperm_f(src_byte, lin[1]);
            const float l2 = bperm_f(src_byte, lin[2]);
            const float l3 = bperm_f(src_byte, lin[3]);
            const float lina = (p & 1) ? l2 : l0;
            const float linb = (p & 1) ? l3 : l1;
            const float aka = fmaf(paA, qa, pcA) + lina;
            const float akb = fmaf(paB, qb, pcB) + linb;

            float m = fmaxf(aka, akb);
            m = dpp_max<0x124>(m); m = dpp_max<0x128>(m);
            const float ea = __builtin_amdgcn_exp2f(aka - m);
            const float eb = __builtin_amdgcn_exp2f(akb - m);
            float s = ea + eb;
            s = dpp_add<0x124>(s); s = dpp_add<0x128>(s);
            const float inv = __builtin_amdgcn_rcpf(s);
            *(float2*)op = make_float2(ea * inv, eb * inv);
        }
        a0 = b0; a1 = b1;
        lp += 512;
        op += 128;
    }
}

extern "C" void kernel_launch(void* const* d_in, const int* in_sizes, int n_in,
                              void* d_out, int out_size, void* d_ws, size_t ws_size,
                              hipStream_t stream) {
    const float* X    = (const float*)d_in[0];
    const float* mus  = (const float*)d_in[1];
    const float* sig  = (const float*)d_in[2];
    const float* phis = (const float*)d_in[3];
    float* out = (float*)d_out;

    float* ws    = (float*)d_ws;
    float* pa2   = ws;                   // 8 f32
    float* pc    = ws + 8;               // 8 f32
    ushort* Upan = (ushort*)(ws + 16);   // 512 bf16 (1 KiB)
    ushort* Wtg  = (ushort*)(ws + 272);  // 8192 bf16, byte off 1088 (16B-aligned)

    const int N = in_sizes[0] / DDIM;

    gmm_prep<<<KMIX, 1024, 0, stream>>>(sig, mus, phis, Wtg, Upan, pa2, pc);

    const int ntiles = N >> 4;
    const int grid = (ntiles + 4 * TPW - 1) / (4 * TPW);
    gmm_main<<<grid, 256, 0, stream>>>(X, Wtg, Upan, pa2, pc, out, N);
}